// Round 12
// baseline (315.589 us; speedup 1.0000x reference)
//
#include <hip/hip_runtime.h>
#include <hip/hip_bf16.h>
#include <stdint.h>

#define NN 8192
#define MAXNZ 64
#define BN_EPS 1e-5f
#define SLOPE 0.2f
#define IND 1433
#define NPAD 1536

typedef float f32x4v __attribute__((ext_vector_type(4)));
typedef short bf16x8v __attribute__((ext_vector_type(8)));

__device__ __forceinline__ float wave_sum(float v) {
#pragma unroll
  for (int off = 32; off > 0; off >>= 1) v += __shfl_xor(v, off);
  return v;
}
__device__ __forceinline__ float wave_max(float v) {
#pragma unroll
  for (int off = 32; off > 0; off >>= 1) v = fmaxf(v, __shfl_xor(v, off));
  return v;
}

#define GLOAD_LDS16(g, l)                                                      \
  __builtin_amdgcn_global_load_lds(                                            \
      (const __attribute__((address_space(1))) unsigned int*)(g),              \
      (__attribute__((address_space(3))) unsigned int*)(l), 16, 0, 0)

// ---------------- Wh = x @ W_att (f32) + fused colsum(cs) + f1/f2 epilogue
__global__ __launch_bounds__(256) void gemm_att_k(const float* __restrict__ A,
                                                  const float* __restrict__ B,
                                                  const float* __restrict__ aatt,
                                                  float* __restrict__ C,
                                                  float* __restrict__ cs,
                                                  float* __restrict__ f1,
                                                  float* __restrict__ f2) {
  __shared__ float As[64][68];
  __shared__ float Bs[64][68];
  __shared__ float csL[64];
  const int t = threadIdx.x;
  const int m0 = blockIdx.x * 64, n0 = blockIdx.y * 64;
  const int tx = t & 15, ty = t >> 4;
  if (t < 64) csL[t] = 0.f;
  float acc[4][4] = {};
  for (int kt = 0; kt < 128; kt += 64) {
    if (kt) __syncthreads();
#pragma unroll
    for (int i = 0; i < 4; ++i) {
      int fid = t + 256 * i;
      int r = fid >> 4, kq = (fid & 15) * 4;
      float4 v = *(const float4*)&A[(size_t)(m0 + r) * 128 + kt + kq];
      *(float4*)&As[r][kq] = v;
    }
#pragma unroll
    for (int i = 0; i < 4; ++i) {
      int fid = t + 256 * i;
      int r = fid >> 4, cq = (fid & 15) * 4;
      float4 v = *(const float4*)&B[(size_t)(kt + r) * 128 + n0 + cq];
      *(float4*)&Bs[r][cq] = v;
    }
    __syncthreads();
#pragma unroll 4
    for (int k0 = 0; k0 < 64; k0 += 4) {
      float4 a[4], b[4];
#pragma unroll
      for (int i = 0; i < 4; ++i) a[i] = *(const float4*)&As[ty * 4 + i][k0];
#pragma unroll
      for (int j = 0; j < 4; ++j) b[j] = *(const float4*)&Bs[k0 + j][tx * 4];
#pragma unroll
      for (int kk = 0; kk < 4; ++kk) {
#pragma unroll
        for (int i = 0; i < 4; ++i) {
          float av = ((const float*)&a[i])[kk];
#pragma unroll
          for (int j = 0; j < 4; ++j)
            acc[i][j] += av * ((const float*)&b[kk])[j];
        }
      }
    }
  }
#pragma unroll
  for (int i = 0; i < 4; ++i) {
    float4 v = make_float4(acc[i][0], acc[i][1], acc[i][2], acc[i][3]);
    *(float4*)&C[(size_t)(m0 + ty * 4 + i) * 128 + n0 + tx * 4] = v;
  }
  float a1v[4], a2v[4];
#pragma unroll
  for (int j = 0; j < 4; ++j) {
    a1v[j] = aatt[n0 + tx * 4 + j];
    a2v[j] = aatt[128 + n0 + tx * 4 + j];
  }
#pragma unroll
  for (int i = 0; i < 4; ++i) {
    float p1 = acc[i][0] * a1v[0] + acc[i][1] * a1v[1] + acc[i][2] * a1v[2] +
               acc[i][3] * a1v[3];
    float p2 = acc[i][0] * a2v[0] + acc[i][1] * a2v[1] + acc[i][2] * a2v[2] +
               acc[i][3] * a2v[3];
#pragma unroll
    for (int off = 1; off < 16; off <<= 1) {
      p1 += __shfl_xor(p1, off);
      p2 += __shfl_xor(p2, off);
    }
    if ((t & 15) == 0) {
      atomicAdd(&f1[m0 + ty * 4 + i], p1);
      atomicAdd(&f2[m0 + ty * 4 + i], p2);
    }
  }
  float cp[4];
#pragma unroll
  for (int j = 0; j < 4; ++j) {
    cp[j] = acc[0][j] + acc[1][j] + acc[2][j] + acc[3][j];
    cp[j] += __shfl_xor(cp[j], 16);
    cp[j] += __shfl_xor(cp[j], 32);
  }
  if ((t & 63) < 16) {
#pragma unroll
    for (int j = 0; j < 4; ++j) atomicAdd(&csL[(t & 15) * 4 + j], cp[j]);
  }
  __syncthreads();
  if (t < 64) atomicAdd(&cs[n0 + t], csL[t]);
}

// ---------------- FUSED: sparse extract + masked softmax + z = att @ Wh (wave/row)
__global__ void extract_attn_k(const float* __restrict__ adj, const float* __restrict__ Wh,
                               const float* __restrict__ f1, const float* __restrict__ f2,
                               const float* __restrict__ cs, int* __restrict__ nnzA,
                               int* __restrict__ idxA, float* __restrict__ valA,
                               float* __restrict__ valsumA, float* __restrict__ z) {
  __shared__ int idxL[4][MAXNZ];
  __shared__ float valL[4][MAXNZ];
  int l = threadIdx.x & 63, w = threadIdx.x >> 6;
  int i = blockIdx.x * 4 + w;
  const float* row = adj + (size_t)i * NN;
  int base = 0;
  for (int it = 0; it < NN / 256; ++it) {
    float4 v4 = *(const float4*)&row[it * 256 + l * 4];
#pragma unroll
    for (int j = 0; j < 4; ++j) {
      float v = ((const float*)&v4)[j];
      bool p = v > 0.0f;
      unsigned long long m = __ballot(p);
      if (p) {
        int pos = base + (int)__popcll(m & ((1ull << l) - 1ull));
        if (pos < MAXNZ) {
          idxL[w][pos] = it * 256 + l * 4 + j;
          valL[w][pos] = v;
        }
      }
      base += (int)__popcll(m);
    }
  }
  int nnz = base < MAXNZ ? base : MAXNZ;
  if (l == 0) nnzA[i] = nnz;
  __syncthreads();  // make each wave's compacted idx/val visible across its lanes

  int c = -1;
  float v = 0.f, att = 0.f;
  if (l < nnz) { c = idxL[w][l]; v = valL[w][l]; }
  idxA[(size_t)i * MAXNZ + l] = (l < nnz) ? c : 0;
  valA[(size_t)i * MAXNZ + l] = v;
  float vs = wave_sum(v);
  if (l == 0) valsumA[i] = vs;

  if (nnz == 0) {
    const float inv = 1.0f / 8192.0f;
    z[(size_t)i * 128 + l] = cs[l] * inv;
    z[(size_t)i * 128 + 64 + l] = cs[64 + l] * inv;
    return;
  }
  float e = -INFINITY;
  if (l < nnz) {
    float u = f1[i] + f2[c];
    e = u >= 0.f ? u : SLOPE * u;
  }
  float mx = wave_max(e);
  float p = (l < nnz) ? expf(e - mx) : 0.f;
  float s = wave_sum(p);
  att = p / s;
  float a0 = 0.f, a1 = 0.f;
  for (int j = 0; j < nnz; ++j) {
    float wt = __shfl(att, j);
    int r = __shfl(c, j);
    a0 += wt * Wh[(size_t)r * 128 + l];
    a1 += wt * Wh[(size_t)r * 128 + 64 + l];
  }
  z[(size_t)i * 128 + l] = a0;
  z[(size_t)i * 128 + 64 + l] = a1;
}

// ---------------- g = adj @ z  (wave per row, f32 in -> bf16 out, shfl-broadcast)
__global__ void gather_z_k(const float* __restrict__ X, const int* __restrict__ nnzA,
                           const int* __restrict__ idxA, const float* __restrict__ valA,
                           __hip_bfloat16* __restrict__ Y) {
  int l = threadIdx.x & 63, w = threadIdx.x >> 6;
  int i = blockIdx.x * 4 + w;
  int nnz = nnzA[i];
  int myi = idxA[(size_t)i * MAXNZ + l];
  float myv = valA[(size_t)i * MAXNZ + l];
  float a0 = 0.f, a1 = 0.f;
  for (int j = 0; j < nnz; ++j) {
    int r = __shfl(myi, j);
    float v = __shfl(myv, j);
    a0 += v * X[(size_t)r * 128 + l];
    a1 += v * X[(size_t)r * 128 + 64 + l];
  }
  Y[(size_t)i * 128 + l] = __float2bfloat16(a0);
  Y[(size_t)i * 128 + 64 + l] = __float2bfloat16(a1);
}

// ---------------- FUSED: s1 = BN3(t[:,256:512]) ; gh = BN1-affine gather of t[:,:256]
__global__ void s1_gather_k(const __hip_bfloat16* __restrict__ t, const int* __restrict__ nnzA,
                            const int* __restrict__ idxA, const float* __restrict__ valA,
                            const float* __restrict__ valsumA, const float* __restrict__ sums,
                            const float* __restrict__ sumsq, const float* __restrict__ g1,
                            const float* __restrict__ b1, const float* __restrict__ g3,
                            const float* __restrict__ b3, __hip_bfloat16* __restrict__ s1b,
                            __hip_bfloat16* __restrict__ ghb) {
  __shared__ int idxL[MAXNZ];
  __shared__ float valL[MAXNZ];
  int i = blockIdx.x, tt = threadIdx.x;
  int nnz = nnzA[i];
  if (tt < MAXNZ) {
    idxL[tt] = idxA[(size_t)i * MAXNZ + tt];
    valL[tt] = valA[(size_t)i * MAXNZ + tt];
  }
  __syncthreads();
  {
    float m = sums[256 + tt] * (1.f / 8192.f);
    float va = fmaxf(sumsq[256 + tt] * (1.f / 8192.f) - m * m, 0.f);
    float sc = g3[tt] * rsqrtf(va + BN_EPS);
    float sh = b3[tt] - m * sc;
    float v = __bfloat162float(t[(size_t)i * 512 + 256 + tt]) * sc + sh;
    s1b[(size_t)i * 256 + tt] = __float2bfloat16(v);
  }
  float acc = 0.f;
  for (int j = 0; j < nnz; ++j)
    acc += valL[j] * __bfloat162float(t[(size_t)idxL[j] * 512 + tt]);
  float m = sums[tt] * (1.f / 8192.f);
  float va = fmaxf(sumsq[tt] * (1.f / 8192.f) - m * m, 0.f);
  float sc = g1[tt] * rsqrtf(va + BN_EPS);
  float sh = b1[tt] - m * sc;
  ghb[(size_t)i * 256 + tt] = __float2bfloat16(acc * sc + sh * valsumA[i]);
}

// ---------------- feat final: inline BN2 finalize + apply -> f32 out (G13-vectorized)
// Thread t (t<192) handles 8 contiguous cols: short8 load + 2x float4 store.
__global__ void feat_apply_k(const __hip_bfloat16* __restrict__ fp, const float* __restrict__ sums,
                             const float* __restrict__ sumsq, const float* __restrict__ g,
                             const float* __restrict__ b, float* __restrict__ out) {
  int i = blockIdx.x, t = threadIdx.x;
  if (t >= 192) return;
  int c0 = t * 8;
  float sc[8], sh[8];
#pragma unroll
  for (int q = 0; q < 8; ++q) {
    int c = c0 + q;
    if (c < IND) {
      float m = sums[c] * (1.f / 8192.f);
      float va = fmaxf(sumsq[c] * (1.f / 8192.f) - m * m, 0.f);
      sc[q] = g[c] * rsqrtf(va + BN_EPS);
      sh[q] = b[c] - m * sc[q];
    } else {
      sc[q] = 0.f;
      sh[q] = 0.f;
    }
  }
  bf16x8v v8 = *(const bf16x8v*)&fp[(size_t)i * NPAD + c0];
  float o[8];
#pragma unroll
  for (int q = 0; q < 8; ++q) {
    union { unsigned int x; float f; } cv;
    cv.x = ((unsigned int)(unsigned short)v8[q]) << 16;
    o[q] = cv.f * sc[q] + sh[q];
  }
  if (c0 + 8 <= IND) {
    *(float4*)&out[(size_t)i * IND + c0] = make_float4(o[0], o[1], o[2], o[3]);
    *(float4*)&out[(size_t)i * IND + c0 + 4] = make_float4(o[4], o[5], o[6], o[7]);
  } else {
#pragma unroll
    for (int q = 0; q < 8; ++q)
      if (c0 + q < IND) out[(size_t)i * IND + c0 + q] = o[q];
  }
}

// ---------------- prep: Wt = W_fd2^T bf16 [1536][256]; Wcatb = [W_fd1|W_sd1]^T bf16 [512][128]
__global__ void prep_k(const float* __restrict__ W_fd2, const float* __restrict__ W_fd1,
                       const float* __restrict__ W_sd1, __hip_bfloat16* __restrict__ Wt,
                       __hip_bfloat16* __restrict__ Wcatb) {
  int b = blockIdx.x, t = threadIdx.x;
  int o = b * 256 + t;
  int n = o >> 8, k = o & 255;
  Wt[o] = __float2bfloat16(n < IND ? W_fd2[(size_t)k * IND + n] : 0.f);
  if (b < 256) {
    int nn = o >> 7, kk = o & 127;
    float v = nn < 256 ? W_fd1[(size_t)kk * 256 + nn] : W_sd1[(size_t)kk * 256 + (nn - 256)];
    Wcatb[o] = __float2bfloat16(v);
  }
}

// ---------------- bf16 MFMA GEMM (KT K-tiles of 128): relu+bf16 store + fused BN stats
template <int KT>
__global__ __launch_bounds__(256) void mfma_bt_k(const short* __restrict__ A,
                                                 const short* __restrict__ Bt,
                                                 __hip_bfloat16* __restrict__ C, int ldc,
                                                 int gridN, float* __restrict__ sums,
                                                 float* __restrict__ sumsq) {
  __shared__ short lds[2][16384];
  const int nwg = gridDim.x;
  const int cpx = nwg >> 3;
  const int bid = blockIdx.x;
  const int wg = (bid & 7) * cpx + (bid >> 3);
  const int m0 = (wg / gridN) * 128, n0 = (wg % gridN) * 128;
  const int t = threadIdx.x;
  const int l = t & 63, w = t >> 6;
  const int wm = w >> 1, wn = w & 1;
  const int KW = KT * 128;
  f32x4v acc[4][4];
#pragma unroll
  for (int i = 0; i < 4; ++i)
#pragma unroll
    for (int j = 0; j < 4; ++j)
#pragma unroll
      for (int q = 0; q < 4; ++q) acc[i][j][q] = 0.f;

  for (int kt = 0; kt < KT; ++kt) {
    if (kt) __syncthreads();
#pragma unroll
    for (int i = 0; i < 8; ++i) {
      int region = w * 8 + i;
      int lr = region * 4 + (l >> 4);
      int ch = (l & 15) ^ (lr & 7);
      const short* gA = A + ((size_t)(m0 + lr) * KW + kt * 128 + ch * 8);
      GLOAD_LDS16(gA, &lds[0][region * 512]);
      const short* gB = Bt + ((size_t)(n0 + lr) * KW + kt * 128 + ch * 8);
      GLOAD_LDS16(gB, &lds[1][region * 512]);
    }
    __syncthreads();
#pragma unroll
    for (int ks = 0; ks < 4; ++ks) {
      bf16x8v af[4], bf[4];
#pragma unroll
      for (int mi = 0; mi < 4; ++mi) {
        int lr = wm * 64 + mi * 16 + (l & 15);
        int ch = (ks * 4 + (l >> 4)) ^ (lr & 7);
        af[mi] = *(const bf16x8v*)&lds[0][lr * 128 + ch * 8];
      }
#pragma unroll
      for (int nj = 0; nj < 4; ++nj) {
        int lr = wn * 64 + nj * 16 + (l & 15);
        int ch = (ks * 4 + (l >> 4)) ^ (lr & 7);
        bf[nj] = *(const bf16x8v*)&lds[1][lr * 128 + ch * 8];
      }
#pragma unroll
      for (int mi = 0; mi < 4; ++mi)
#pragma unroll
        for (int nj = 0; nj < 4; ++nj)
          acc[mi][nj] = __builtin_amdgcn_mfma_f32_16x16x32_bf16(
              af[mi], bf[nj], acc[mi][nj], 0, 0, 0);
    }
  }
#pragma unroll
  for (int nj = 0; nj < 4; ++nj) {
    int col = n0 + wn * 64 + nj * 16 + (l & 15);
    float s = 0.f, ss = 0.f;
#pragma unroll
    for (int mi = 0; mi < 4; ++mi) {
#pragma unroll
      for (int q = 0; q < 4; ++q) {
        int row = m0 + wm * 64 + mi * 16 + (l >> 4) * 4 + q;
        float v = fmaxf(acc[mi][nj][q], 0.f);
        C[(size_t)row * ldc + col] = __float2bfloat16(v);
        s += v;
        ss += v * v;
      }
    }
    s += __shfl_xor(s, 16);
    s += __shfl_xor(s, 32);
    ss += __shfl_xor(ss, 16);
    ss += __shfl_xor(ss, 32);
    if ((l >> 4) == 0) {
      atomicAdd(&sums[col], s);
      atomicAdd(&sumsq[col], ss);
    }
  }
}

// ---------------- FUSED TAIL (R6-proven config): feat GEMM (768) + struct sym
// (2080) interleaved; BK=128, 64 KB LDS staging.
__global__ __launch_bounds__(256) void tail_k(const short* __restrict__ Agh,
                                              const short* __restrict__ Wt,
                                              __hip_bfloat16* __restrict__ featb,
                                              float* __restrict__ sums,
                                              float* __restrict__ sumsq,
                                              const short* __restrict__ S,
                                              float* __restrict__ C) {
  __shared__ short lds[2][16384];
  const int bid = blockIdx.x;
  const int fA = bid * 24 / 89;
  const bool isFeat = ((bid + 1) * 24 / 89) > fA;
  const int t = threadIdx.x;
  const int l = t & 63, w = t >> 6;
  const int wm = w >> 1, wn = w & 1;

  const short* Ab;
  const short* Bb;
  int m0, n0, bi = 0, bj = 0;
  if (isFeat) {
    const int fb = fA;  // 0..767
    const int wg = (fb & 7) * 96 + (fb >> 3);
    m0 = (wg / 12) * 128;
    n0 = (wg % 12) * 128;
    Ab = Agh;
    Bb = Wt;
  } else {
    const int sb = bid - fA;  // 0..2079
    const int wg = (sb & 7) * 260 + (sb >> 3);
    bi = (int)((129.0f - sqrtf(16641.0f - 8.0f * (float)wg)) * 0.5f);
    while ((bi + 1) * 64 - ((bi + 1) * bi) / 2 <= wg) ++bi;
    while (bi * 64 - (bi * (bi - 1)) / 2 > wg) --bi;
    bj = bi + (wg - (bi * 64 - (bi * (bi - 1)) / 2));
    m0 = bi * 128;
    n0 = bj * 128;
    Ab = S;
    Bb = S;
  }

  f32x4v acc[4][4];
#pragma unroll
  for (int i = 0; i < 4; ++i)
#pragma unroll
    for (int j = 0; j < 4; ++j)
#pragma unroll
      for (int q = 0; q < 4; ++q) acc[i][j][q] = 0.f;

  for (int kt = 0; kt < 2; ++kt) {
    if (kt) __syncthreads();
#pragma unroll
    for (int i = 0; i < 8; ++i) {
      int region = w * 8 + i;
      int lr = region * 4 + (l >> 4);
      int ch = (l & 15) ^ (lr & 7);
      const short* gA = Ab + ((size_t)(m0 + lr) * 256 + kt * 128 + ch * 8);
      GLOAD_LDS16(gA, &lds[0][region * 512]);
      const short* gB = Bb + ((size_t)(n0 + lr) * 256 + kt * 128 + ch * 8);
      GLOAD_LDS16(gB, &lds[1][region * 512]);
    }
    __syncthreads();
#pragma unroll
    for (int ks = 0; ks < 4; ++ks) {
      bf16x8v af[4], bf[4];
#pragma unroll
      for (int mi = 0; mi < 4; ++mi) {
        int lr = wm * 64 + mi * 16 + (l & 15);
        int ch = (ks * 4 + (l >> 4)) ^ (lr & 7);
        af[mi] = *(const bf16x8v*)&lds[0][lr * 128 + ch * 8];
      }
#pragma unroll
      for (int nj = 0; nj < 4; ++nj) {
        int lr = wn * 64 + nj * 16 + (l & 15);
        int ch = (ks * 4 + (l >> 4)) ^ (lr & 7);
        bf[nj] = *(const bf16x8v*)&lds[1][lr * 128 + ch * 8];
      }
#pragma unroll
      for (int mi = 0; mi < 4; ++mi)
#pragma unroll
        for (int nj = 0; nj < 4; ++nj)
          acc[mi][nj] = __builtin_amdgcn_mfma_f32_16x16x32_bf16(
              af[mi], bf[nj], acc[mi][nj], 0, 0, 0);
    }
  }

  if (isFeat) {
#pragma unroll
    for (int nj = 0; nj < 4; ++nj) {
      int col = n0 + wn * 64 + nj * 16 + (l & 15);
      float s = 0.f, ss = 0.f;
#pragma unroll
      for (int mi = 0; mi < 4; ++mi) {
#pragma unroll
        for (int q = 0; q < 4; ++q) {
          int row = m0 + wm * 64 + mi * 16 + (l >> 4) * 4 + q;
          float v = fmaxf(acc[mi][nj][q], 0.f);
          featb[(size_t)row * NPAD + col] = __float2bfloat16(v);
          s += v;
          ss += v * v;
        }
      }
      s += __shfl_xor(s, 16);
      s += __shfl_xor(s, 32);
      ss += __shfl_xor(ss, 16);
      ss += __shfl_xor(ss, 32);
      if ((l >> 4) == 0) {
        atomicAdd(&sums[col], s);
        atomicAdd(&sumsq[col], ss);
      }
    }
  } else {
#pragma unroll
    for (int mi = 0; mi < 4; ++mi) {
#pragma unroll
      for (int nj = 0; nj < 4; ++nj) {
        int col = n0 + wn * 64 + nj * 16 + (l & 15);
#pragma unroll
        for (int q = 0; q < 4; ++q) {
          int row = m0 + wm * 64 + mi * 16 + (l >> 4) * 4 + q;
          C[(size_t)row * NN + col] = acc[mi][nj][q];
        }
      }
    }
    if (bi != bj) {
#pragma unroll
      for (int nj = 0; nj < 4; ++nj) {
        int col = n0 + wn * 64 + nj * 16 + (l & 15);
#pragma unroll
        for (int mi = 0; mi < 4; ++mi) {
          int row0 = m0 + wm * 64 + mi * 16 + (l >> 4) * 4;
          float4 v = make_float4(acc[mi][nj][0], acc[mi][nj][1], acc[mi][nj][2],
                                 acc[mi][nj][3]);
          *(float4*)&C[(size_t)col * NN + row0] = v;
        }
      }
    }
  }
}

extern "C" void kernel_launch(void* const* d_in, const int* in_sizes, int n_in,
                              void* d_out, int out_size, void* d_ws, size_t ws_size,
                              hipStream_t stream) {
  const float* x = (const float*)d_in[0];
  const float* adj = (const float*)d_in[1];
  const float* W_att = (const float*)d_in[2];
  const float* a_att = (const float*)d_in[3];
  const float* W_fd1 = (const float*)d_in[4];
  const float* bn1g = (const float*)d_in[5];
  const float* bn1b = (const float*)d_in[6];
  const float* W_fd2 = (const float*)d_in[7];
  const float* bn2g = (const float*)d_in[8];
  const float* bn2b = (const float*)d_in[9];
  const float* W_sd1 = (const float*)d_in[10];
  const float* bn3g = (const float*)d_in[11];
  const float* bn3b = (const float*)d_in[12];

  float* out = (float*)d_out;
  float* feat_out = out;                           // [8192][1433]
  float* struct_out = out + (size_t)NN * IND;      // [8192][8192]

  float* ws = (float*)d_ws;
  size_t off = 0;
  auto alloc = [&](size_t nfloats) {
    float* p = ws + off;
    off += (nfloats + 255) & ~(size_t)255;
    return p;
  };
  float* Wh = alloc((size_t)NN * 128);
  float* z = alloc((size_t)NN * 128);
  float* valsum = alloc(NN);
  // contiguous zero region: cs(256) f1(8192) f2(8192) sumsA(512) sumsqA(512)
  //                         sumsB(1536) sumsqB(1536)
  const size_t ZTOT = 256 + 8192 + 8192 + 512 + 512 + 1536 + 1536;
  float* zbase = alloc(ZTOT);
  float* cs = zbase;
  float* f1 = zbase + 256;
  float* f2 = zbase + 256 + 8192;
  float* sumsA = zbase + 256 + 16384;
  float* sumsqA = sumsA + 512;
  float* sumsB = sumsqA + 512;
  float* sumsqB = sumsB + 1536;
  float* valA = alloc((size_t)NN * MAXNZ);
  int* idxA = (int*)alloc((size_t)NN * MAXNZ);
  int* nnzA = (int*)alloc(NN);
  __hip_bfloat16* tbuf = (__hip_bfloat16*)alloc((size_t)NN * 256);  // [8192][512] bf16
  __hip_bfloat16* gb = (__hip_bfloat16*)alloc((size_t)NN * 64);
  __hip_bfloat16* s1b = (__hip_bfloat16*)alloc((size_t)NN * 128);
  __hip_bfloat16* ghb = (__hip_bfloat16*)alloc((size_t)NN * 128);
  __hip_bfloat16* Wt = (__hip_bfloat16*)alloc((size_t)NPAD * 128);
  __hip_bfloat16* Wcatb = (__hip_bfloat16*)alloc(512 * 64);
  __hip_bfloat16* featb = (__hip_bfloat16*)alloc((size_t)NN * NPAD / 2);

  hipMemsetAsync(zbase, 0, ZTOT * sizeof(float), stream);

  // --- weights prep (independent) ---
  prep_k<<<NPAD, 256, 0, stream>>>(W_fd2, W_fd1, W_sd1, Wt, Wcatb);

  // --- GAT encoder ---
  gemm_att_k<<<dim3(NN / 64, 2), 256, 0, stream>>>(x, W_att, a_att, Wh, cs, f1, f2);
  extract_attn_k<<<NN / 4, 256, 0, stream>>>(adj, Wh, f1, f2, cs, nnzA, idxA, valA,
                                             valsum, z);
  gather_z_k<<<NN / 4, 256, 0, stream>>>(z, nnzA, idxA, valA, gb);

  // --- t = relu(g @ [W_fd1|W_sd1]) bf16 (MFMA, fused BN1/BN3 stats) ---
  mfma_bt_k<1><<<64 * 4, 256, 0, stream>>>((const short*)gb, (const short*)Wcatb,
                                           tbuf, 512, 4, sumsA, sumsqA);
  s1_gather_k<<<NN, 256, 0, stream>>>(tbuf, nnzA, idxA, valA, valsum, sumsA, sumsqA,
                                      bn1g, bn1b, bn3g, bn3b, s1b, ghb);

  // --- fused tail: feat GEMM (+BN2 stats) interleaved with struct sym ---
  tail_k<<<2848, 256, 0, stream>>>((const short*)ghb, (const short*)Wt, featb,
                                   sumsB, sumsqB, (const short*)s1b, struct_out);
  feat_apply_k<<<NN, 256, 0, stream>>>(featb, sumsB, sumsqB, bn2g, bn2b, feat_out);
}

// Round 13
// 248.651 us; speedup vs baseline: 1.2692x; 1.2692x over previous
//
#include <hip/hip_runtime.h>
#include <hip/hip_bf16.h>
#include <stdint.h>

#define NN 8192
#define MAXNZ 64
#define BN_EPS 1e-5f
#define SLOPE 0.2f
#define IND 1433
#define NPAD 1536

typedef float f32x4v __attribute__((ext_vector_type(4)));
typedef short bf16x8v __attribute__((ext_vector_type(8)));

__device__ __forceinline__ float wave_sum(float v) {
#pragma unroll
  for (int off = 32; off > 0; off >>= 1) v += __shfl_xor(v, off);
  return v;
}
__device__ __forceinline__ float wave_max(float v) {
#pragma unroll
  for (int off = 32; off > 0; off >>= 1) v = fmaxf(v, __shfl_xor(v, off));
  return v;
}

#define GLOAD_LDS16(g, l)                                                      \
  __builtin_amdgcn_global_load_lds(                                            \
      (const __attribute__((address_space(1))) unsigned int*)(g),              \
      (__attribute__((address_space(3))) unsigned int*)(l), 16, 0, 0)

// ---------------- Wh = x @ W_att (f32) + fused colsum(cs) + f1/f2 epilogue
__global__ __launch_bounds__(256) void gemm_att_k(const float* __restrict__ A,
                                                  const float* __restrict__ B,
                                                  const float* __restrict__ aatt,
                                                  float* __restrict__ C,
                                                  float* __restrict__ cs,
                                                  float* __restrict__ f1,
                                                  float* __restrict__ f2) {
  __shared__ float As[64][68];
  __shared__ float Bs[64][68];
  __shared__ float csL[64];
  const int t = threadIdx.x;
  const int m0 = blockIdx.x * 64, n0 = blockIdx.y * 64;
  const int tx = t & 15, ty = t >> 4;
  if (t < 64) csL[t] = 0.f;
  float acc[4][4] = {};
  for (int kt = 0; kt < 128; kt += 64) {
    if (kt) __syncthreads();
#pragma unroll
    for (int i = 0; i < 4; ++i) {
      int fid = t + 256 * i;
      int r = fid >> 4, kq = (fid & 15) * 4;
      float4 v = *(const float4*)&A[(size_t)(m0 + r) * 128 + kt + kq];
      *(float4*)&As[r][kq] = v;
    }
#pragma unroll
    for (int i = 0; i < 4; ++i) {
      int fid = t + 256 * i;
      int r = fid >> 4, cq = (fid & 15) * 4;
      float4 v = *(const float4*)&B[(size_t)(kt + r) * 128 + n0 + cq];
      *(float4*)&Bs[r][cq] = v;
    }
    __syncthreads();
#pragma unroll 4
    for (int k0 = 0; k0 < 64; k0 += 4) {
      float4 a[4], b[4];
#pragma unroll
      for (int i = 0; i < 4; ++i) a[i] = *(const float4*)&As[ty * 4 + i][k0];
#pragma unroll
      for (int j = 0; j < 4; ++j) b[j] = *(const float4*)&Bs[k0 + j][tx * 4];
#pragma unroll
      for (int kk = 0; kk < 4; ++kk) {
#pragma unroll
        for (int i = 0; i < 4; ++i) {
          float av = ((const float*)&a[i])[kk];
#pragma unroll
          for (int j = 0; j < 4; ++j)
            acc[i][j] += av * ((const float*)&b[kk])[j];
        }
      }
    }
  }
#pragma unroll
  for (int i = 0; i < 4; ++i) {
    float4 v = make_float4(acc[i][0], acc[i][1], acc[i][2], acc[i][3]);
    *(float4*)&C[(size_t)(m0 + ty * 4 + i) * 128 + n0 + tx * 4] = v;
  }
  float a1v[4], a2v[4];
#pragma unroll
  for (int j = 0; j < 4; ++j) {
    a1v[j] = aatt[n0 + tx * 4 + j];
    a2v[j] = aatt[128 + n0 + tx * 4 + j];
  }
#pragma unroll
  for (int i = 0; i < 4; ++i) {
    float p1 = acc[i][0] * a1v[0] + acc[i][1] * a1v[1] + acc[i][2] * a1v[2] +
               acc[i][3] * a1v[3];
    float p2 = acc[i][0] * a2v[0] + acc[i][1] * a2v[1] + acc[i][2] * a2v[2] +
               acc[i][3] * a2v[3];
#pragma unroll
    for (int off = 1; off < 16; off <<= 1) {
      p1 += __shfl_xor(p1, off);
      p2 += __shfl_xor(p2, off);
    }
    if ((t & 15) == 0) {
      atomicAdd(&f1[m0 + ty * 4 + i], p1);
      atomicAdd(&f2[m0 + ty * 4 + i], p2);
    }
  }
  float cp[4];
#pragma unroll
  for (int j = 0; j < 4; ++j) {
    cp[j] = acc[0][j] + acc[1][j] + acc[2][j] + acc[3][j];
    cp[j] += __shfl_xor(cp[j], 16);
    cp[j] += __shfl_xor(cp[j], 32);
  }
  if ((t & 63) < 16) {
#pragma unroll
    for (int j = 0; j < 4; ++j) atomicAdd(&csL[(t & 15) * 4 + j], cp[j]);
  }
  __syncthreads();
  if (t < 64) atomicAdd(&cs[n0 + t], csL[t]);
}

// ---------------- FUSED: sparse extract + masked softmax + z = att @ Wh (wave/row)
__global__ void extract_attn_k(const float* __restrict__ adj, const float* __restrict__ Wh,
                               const float* __restrict__ f1, const float* __restrict__ f2,
                               const float* __restrict__ cs, int* __restrict__ nnzA,
                               int* __restrict__ idxA, float* __restrict__ valA,
                               float* __restrict__ valsumA, float* __restrict__ z) {
  __shared__ int idxL[4][MAXNZ];
  __shared__ float valL[4][MAXNZ];
  int l = threadIdx.x & 63, w = threadIdx.x >> 6;
  int i = blockIdx.x * 4 + w;
  const float* row = adj + (size_t)i * NN;
  int base = 0;
  for (int it = 0; it < NN / 256; ++it) {
    float4 v4 = *(const float4*)&row[it * 256 + l * 4];
#pragma unroll
    for (int j = 0; j < 4; ++j) {
      float v = ((const float*)&v4)[j];
      bool p = v > 0.0f;
      unsigned long long m = __ballot(p);
      if (p) {
        int pos = base + (int)__popcll(m & ((1ull << l) - 1ull));
        if (pos < MAXNZ) {
          idxL[w][pos] = it * 256 + l * 4 + j;
          valL[w][pos] = v;
        }
      }
      base += (int)__popcll(m);
    }
  }
  int nnz = base < MAXNZ ? base : MAXNZ;
  if (l == 0) nnzA[i] = nnz;
  __syncthreads();  // make each wave's compacted idx/val visible across its lanes

  int c = -1;
  float v = 0.f, att = 0.f;
  if (l < nnz) { c = idxL[w][l]; v = valL[w][l]; }
  idxA[(size_t)i * MAXNZ + l] = (l < nnz) ? c : 0;
  valA[(size_t)i * MAXNZ + l] = v;
  float vs = wave_sum(v);
  if (l == 0) valsumA[i] = vs;

  if (nnz == 0) {
    const float inv = 1.0f / 8192.0f;
    z[(size_t)i * 128 + l] = cs[l] * inv;
    z[(size_t)i * 128 + 64 + l] = cs[64 + l] * inv;
    return;
  }
  float e = -INFINITY;
  if (l < nnz) {
    float u = f1[i] + f2[c];
    e = u >= 0.f ? u : SLOPE * u;
  }
  float mx = wave_max(e);
  float p = (l < nnz) ? expf(e - mx) : 0.f;
  float s = wave_sum(p);
  att = p / s;
  float a0 = 0.f, a1 = 0.f;
  for (int j = 0; j < nnz; ++j) {
    float wt = __shfl(att, j);
    int r = __shfl(c, j);
    a0 += wt * Wh[(size_t)r * 128 + l];
    a1 += wt * Wh[(size_t)r * 128 + 64 + l];
  }
  z[(size_t)i * 128 + l] = a0;
  z[(size_t)i * 128 + 64 + l] = a1;
}

// ---------------- g = adj @ z  (wave per row, f32 in -> bf16 out)
__global__ void gather_z_k(const float* __restrict__ X, const int* __restrict__ nnzA,
                           const int* __restrict__ idxA, const float* __restrict__ valA,
                           __hip_bfloat16* __restrict__ Y) {
  int l = threadIdx.x & 63, w = threadIdx.x >> 6;
  int i = blockIdx.x * 4 + w;
  int nnz = nnzA[i];
  float a0 = 0.f, a1 = 0.f;
  for (int j = 0; j < nnz; ++j) {
    int r = idxA[(size_t)i * MAXNZ + j];
    float v = valA[(size_t)i * MAXNZ + j];
    a0 += v * X[(size_t)r * 128 + l];
    a1 += v * X[(size_t)r * 128 + 64 + l];
  }
  Y[(size_t)i * 128 + l] = __float2bfloat16(a0);
  Y[(size_t)i * 128 + 64 + l] = __float2bfloat16(a1);
}

// ---------------- FUSED: s1 = BN3(t[:,256:512]) ; gh = BN1-affine gather of t[:,:256]
__global__ void s1_gather_k(const __hip_bfloat16* __restrict__ t, const int* __restrict__ nnzA,
                            const int* __restrict__ idxA, const float* __restrict__ valA,
                            const float* __restrict__ valsumA, const float* __restrict__ sums,
                            const float* __restrict__ sumsq, const float* __restrict__ g1,
                            const float* __restrict__ b1, const float* __restrict__ g3,
                            const float* __restrict__ b3, __hip_bfloat16* __restrict__ s1b,
                            __hip_bfloat16* __restrict__ ghb) {
  __shared__ int idxL[MAXNZ];
  __shared__ float valL[MAXNZ];
  int i = blockIdx.x, tt = threadIdx.x;
  int nnz = nnzA[i];
  if (tt < MAXNZ) {
    idxL[tt] = idxA[(size_t)i * MAXNZ + tt];
    valL[tt] = valA[(size_t)i * MAXNZ + tt];
  }
  __syncthreads();
  {
    float m = sums[256 + tt] * (1.f / 8192.f);
    float va = fmaxf(sumsq[256 + tt] * (1.f / 8192.f) - m * m, 0.f);
    float sc = g3[tt] * rsqrtf(va + BN_EPS);
    float sh = b3[tt] - m * sc;
    float v = __bfloat162float(t[(size_t)i * 512 + 256 + tt]) * sc + sh;
    s1b[(size_t)i * 256 + tt] = __float2bfloat16(v);
  }
  float acc = 0.f;
  for (int j = 0; j < nnz; ++j)
    acc += valL[j] * __bfloat162float(t[(size_t)idxL[j] * 512 + tt]);
  float m = sums[tt] * (1.f / 8192.f);
  float va = fmaxf(sumsq[tt] * (1.f / 8192.f) - m * m, 0.f);
  float sc = g1[tt] * rsqrtf(va + BN_EPS);
  float sh = b1[tt] - m * sc;
  ghb[(size_t)i * 256 + tt] = __float2bfloat16(acc * sc + sh * valsumA[i]);
}

// ---------------- feat final: inline BN2 finalize + apply -> f32 out
__global__ void feat_apply_k(const __hip_bfloat16* __restrict__ fp, const float* __restrict__ sums,
                             const float* __restrict__ sumsq, const float* __restrict__ g,
                             const float* __restrict__ b, float* __restrict__ out) {
  int i = blockIdx.x;
  for (int c = threadIdx.x; c < IND; c += 256) {
    float m = sums[c] * (1.f / 8192.f);
    float va = fmaxf(sumsq[c] * (1.f / 8192.f) - m * m, 0.f);
    float sc = g[c] * rsqrtf(va + BN_EPS);
    float sh = b[c] - m * sc;
    out[(size_t)i * IND + c] = __bfloat162float(fp[(size_t)i * NPAD + c]) * sc + sh;
  }
}

// ---------------- prep: Wt = W_fd2^T bf16 [1536][256]; Wcatb = [W_fd1|W_sd1]^T bf16 [512][128]
__global__ void prep_k(const float* __restrict__ W_fd2, const float* __restrict__ W_fd1,
                       const float* __restrict__ W_sd1, __hip_bfloat16* __restrict__ Wt,
                       __hip_bfloat16* __restrict__ Wcatb) {
  int b = blockIdx.x, t = threadIdx.x;
  int o = b * 256 + t;
  int n = o >> 8, k = o & 255;
  Wt[o] = __float2bfloat16(n < IND ? W_fd2[(size_t)k * IND + n] : 0.f);
  if (b < 256) {
    int nn = o >> 7, kk = o & 127;
    float v = nn < 256 ? W_fd1[(size_t)kk * 256 + nn] : W_sd1[(size_t)kk * 256 + (nn - 256)];
    Wcatb[o] = __float2bfloat16(v);
  }
}

// ---------------- bf16 MFMA GEMM (KT K-tiles of 128): relu+bf16 store + fused BN stats
template <int KT>
__global__ __launch_bounds__(256) void mfma_bt_k(const short* __restrict__ A,
                                                 const short* __restrict__ Bt,
                                                 __hip_bfloat16* __restrict__ C, int ldc,
                                                 int gridN, float* __restrict__ sums,
                                                 float* __restrict__ sumsq) {
  __shared__ short lds[2][16384];
  const int nwg = gridDim.x;
  const int cpx = nwg >> 3;
  const int bid = blockIdx.x;
  const int wg = (bid & 7) * cpx + (bid >> 3);
  const int m0 = (wg / gridN) * 128, n0 = (wg % gridN) * 128;
  const int t = threadIdx.x;
  const int l = t & 63, w = t >> 6;
  const int wm = w >> 1, wn = w & 1;
  const int KW = KT * 128;
  f32x4v acc[4][4];
#pragma unroll
  for (int i = 0; i < 4; ++i)
#pragma unroll
    for (int j = 0; j < 4; ++j)
#pragma unroll
      for (int q = 0; q < 4; ++q) acc[i][j][q] = 0.f;

  for (int kt = 0; kt < KT; ++kt) {
    if (kt) __syncthreads();
#pragma unroll
    for (int i = 0; i < 8; ++i) {
      int region = w * 8 + i;
      int lr = region * 4 + (l >> 4);
      int ch = (l & 15) ^ (lr & 7);
      const short* gA = A + ((size_t)(m0 + lr) * KW + kt * 128 + ch * 8);
      GLOAD_LDS16(gA, &lds[0][region * 512]);
      const short* gB = Bt + ((size_t)(n0 + lr) * KW + kt * 128 + ch * 8);
      GLOAD_LDS16(gB, &lds[1][region * 512]);
    }
    __syncthreads();
#pragma unroll
    for (int ks = 0; ks < 4; ++ks) {
      bf16x8v af[4], bf[4];
#pragma unroll
      for (int mi = 0; mi < 4; ++mi) {
        int lr = wm * 64 + mi * 16 + (l & 15);
        int ch = (ks * 4 + (l >> 4)) ^ (lr & 7);
        af[mi] = *(const bf16x8v*)&lds[0][lr * 128 + ch * 8];
      }
#pragma unroll
      for (int nj = 0; nj < 4; ++nj) {
        int lr = wn * 64 + nj * 16 + (l & 15);
        int ch = (ks * 4 + (l >> 4)) ^ (lr & 7);
        bf[nj] = *(const bf16x8v*)&lds[1][lr * 128 + ch * 8];
      }
#pragma unroll
      for (int mi = 0; mi < 4; ++mi)
#pragma unroll
        for (int nj = 0; nj < 4; ++nj)
          acc[mi][nj] = __builtin_amdgcn_mfma_f32_16x16x32_bf16(
              af[mi], bf[nj], acc[mi][nj], 0, 0, 0);
    }
  }
#pragma unroll
  for (int nj = 0; nj < 4; ++nj) {
    int col = n0 + wn * 64 + nj * 16 + (l & 15);
    float s = 0.f, ss = 0.f;
#pragma unroll
    for (int mi = 0; mi < 4; ++mi) {
#pragma unroll
      for (int q = 0; q < 4; ++q) {
        int row = m0 + wm * 64 + mi * 16 + (l >> 4) * 4 + q;
        float v = fmaxf(acc[mi][nj][q], 0.f);
        C[(size_t)row * ldc + col] = __float2bfloat16(v);
        s += v;
        ss += v * v;
      }
    }
    s += __shfl_xor(s, 16);
    s += __shfl_xor(s, 32);
    ss += __shfl_xor(ss, 16);
    ss += __shfl_xor(ss, 32);
    if ((l >> 4) == 0) {
      atomicAdd(&sums[col], s);
      atomicAdd(&sumsq[col], ss);
    }
  }
}

// ---------------- FUSED TAIL: feat GEMM (768) + struct sym (2080) interleaved
__global__ __launch_bounds__(256) void tail_k(const short* __restrict__ Agh,
                                              const short* __restrict__ Wt,
                                              __hip_bfloat16* __restrict__ featb,
                                              float* __restrict__ sums,
                                              float* __restrict__ sumsq,
                                              const short* __restrict__ S,
                                              float* __restrict__ C) {
  __shared__ short lds[2][16384];
  const int bid = blockIdx.x;
  const int fA = bid * 24 / 89;
  const int fB = (bid + 1) * 24 / 89;
  const bool isFeat = fB > fA;
  const int t = threadIdx.x;
  const int l = t & 63, w = t >> 6;
  const int wm = w >> 1, wn = w & 1;
  f32x4v acc[4][4];
#pragma unroll
  for (int i = 0; i < 4; ++i)
#pragma unroll
    for (int j = 0; j < 4; ++j)
#pragma unroll
      for (int q = 0; q < 4; ++q) acc[i][j][q] = 0.f;

  if (isFeat) {
    const int fb = fA;  // 0..767
    const int wg = (fb & 7) * 96 + (fb >> 3);
    const int m0 = (wg / 12) * 128, n0 = (wg % 12) * 128;
    for (int kt = 0; kt < 2; ++kt) {
      if (kt) __syncthreads();
#pragma unroll
      for (int i = 0; i < 8; ++i) {
        int region = w * 8 + i;
        int lr = region * 4 + (l >> 4);
        int ch = (l & 15) ^ (lr & 7);
        const short* gA = Agh + ((size_t)(m0 + lr) * 256 + kt * 128 + ch * 8);
        GLOAD_LDS16(gA, &lds[0][region * 512]);
        const short* gB = Wt + ((size_t)(n0 + lr) * 256 + kt * 128 + ch * 8);
        GLOAD_LDS16(gB, &lds[1][region * 512]);
      }
      __syncthreads();
#pragma unroll
      for (int ks = 0; ks < 4; ++ks) {
        bf16x8v af[4], bf[4];
#pragma unroll
        for (int mi = 0; mi < 4; ++mi) {
          int lr = wm * 64 + mi * 16 + (l & 15);
          int ch = (ks * 4 + (l >> 4)) ^ (lr & 7);
          af[mi] = *(const bf16x8v*)&lds[0][lr * 128 + ch * 8];
        }
#pragma unroll
        for (int nj = 0; nj < 4; ++nj) {
          int lr = wn * 64 + nj * 16 + (l & 15);
          int ch = (ks * 4 + (l >> 4)) ^ (lr & 7);
          bf[nj] = *(const bf16x8v*)&lds[1][lr * 128 + ch * 8];
        }
#pragma unroll
        for (int mi = 0; mi < 4; ++mi)
#pragma unroll
          for (int nj = 0; nj < 4; ++nj)
            acc[mi][nj] = __builtin_amdgcn_mfma_f32_16x16x32_bf16(
                af[mi], bf[nj], acc[mi][nj], 0, 0, 0);
      }
    }
#pragma unroll
    for (int nj = 0; nj < 4; ++nj) {
      int col = n0 + wn * 64 + nj * 16 + (l & 15);
      float s = 0.f, ss = 0.f;
#pragma unroll
      for (int mi = 0; mi < 4; ++mi) {
#pragma unroll
        for (int q = 0; q < 4; ++q) {
          int row = m0 + wm * 64 + mi * 16 + (l >> 4) * 4 + q;
          float v = fmaxf(acc[mi][nj][q], 0.f);
          featb[(size_t)row * NPAD + col] = __float2bfloat16(v);
          s += v;
          ss += v * v;
        }
      }
      s += __shfl_xor(s, 16);
      s += __shfl_xor(s, 32);
      ss += __shfl_xor(ss, 16);
      ss += __shfl_xor(ss, 32);
      if ((l >> 4) == 0) {
        atomicAdd(&sums[col], s);
        atomicAdd(&sumsq[col], ss);
      }
    }
  } else {
    const int sb = bid - fA;  // 0..2079
    const int wg = (sb & 7) * 260 + (sb >> 3);
    int bi = (int)((129.0f - sqrtf(16641.0f - 8.0f * (float)wg)) * 0.5f);
    while ((bi + 1) * 64 - ((bi + 1) * bi) / 2 <= wg) ++bi;
    while (bi * 64 - (bi * (bi - 1)) / 2 > wg) --bi;
    const int bj = bi + (wg - (bi * 64 - (bi * (bi - 1)) / 2));
    const int m0 = bi * 128, n0 = bj * 128;
    for (int kt = 0; kt < 2; ++kt) {
      if (kt) __syncthreads();
#pragma unroll
      for (int i = 0; i < 8; ++i) {
        int region = w * 8 + i;
        int lr = region * 4 + (l >> 4);
        int ch = (l & 15) ^ (lr & 7);
        const short* gA = S + ((size_t)(m0 + lr) * 256 + kt * 128 + ch * 8);
        GLOAD_LDS16(gA, &lds[0][region * 512]);
        const short* gB = S + ((size_t)(n0 + lr) * 256 + kt * 128 + ch * 8);
        GLOAD_LDS16(gB, &lds[1][region * 512]);
      }
      __syncthreads();
#pragma unroll
      for (int ks = 0; ks < 4; ++ks) {
        bf16x8v af[4], bf[4];
#pragma unroll
        for (int mi = 0; mi < 4; ++mi) {
          int lr = wm * 64 + mi * 16 + (l & 15);
          int ch = (ks * 4 + (l >> 4)) ^ (lr & 7);
          af[mi] = *(const bf16x8v*)&lds[0][lr * 128 + ch * 8];
        }
#pragma unroll
        for (int nj = 0; nj < 4; ++nj) {
          int lr = wn * 64 + nj * 16 + (l & 15);
          int ch = (ks * 4 + (l >> 4)) ^ (lr & 7);
          bf[nj] = *(const bf16x8v*)&lds[1][lr * 128 + ch * 8];
        }
#pragma unroll
        for (int mi = 0; mi < 4; ++mi)
#pragma unroll
          for (int nj = 0; nj < 4; ++nj)
            acc[mi][nj] = __builtin_amdgcn_mfma_f32_16x16x32_bf16(
                af[mi], bf[nj], acc[mi][nj], 0, 0, 0);
      }
    }
#pragma unroll
    for (int mi = 0; mi < 4; ++mi) {
#pragma unroll
      for (int nj = 0; nj < 4; ++nj) {
        int col = n0 + wn * 64 + nj * 16 + (l & 15);
#pragma unroll
        for (int q = 0; q < 4; ++q) {
          int row = m0 + wm * 64 + mi * 16 + (l >> 4) * 4 + q;
          C[(size_t)row * NN + col] = acc[mi][nj][q];
        }
      }
    }
    if (bi != bj) {
#pragma unroll
      for (int nj = 0; nj < 4; ++nj) {
        int col = n0 + wn * 64 + nj * 16 + (l & 15);
#pragma unroll
        for (int mi = 0; mi < 4; ++mi) {
          int row0 = m0 + wm * 64 + mi * 16 + (l >> 4) * 4;
          float4 v = make_float4(acc[mi][nj][0], acc[mi][nj][1], acc[mi][nj][2],
                                 acc[mi][nj][3]);
          *(float4*)&C[(size_t)col * NN + row0] = v;
        }
      }
    }
  }
}

extern "C" void kernel_launch(void* const* d_in, const int* in_sizes, int n_in,
                              void* d_out, int out_size, void* d_ws, size_t ws_size,
                              hipStream_t stream) {
  const float* x = (const float*)d_in[0];
  const float* adj = (const float*)d_in[1];
  const float* W_att = (const float*)d_in[2];
  const float* a_att = (const float*)d_in[3];
  const float* W_fd1 = (const float*)d_in[4];
  const float* bn1g = (const float*)d_in[5];
  const float* bn1b = (const float*)d_in[6];
  const float* W_fd2 = (const float*)d_in[7];
  const float* bn2g = (const float*)d_in[8];
  const float* bn2b = (const float*)d_in[9];
  const float* W_sd1 = (const float*)d_in[10];
  const float* bn3g = (const float*)d_in[11];
  const float* bn3b = (const float*)d_in[12];

  float* out = (float*)d_out;
  float* feat_out = out;                           // [8192][1433]
  float* struct_out = out + (size_t)NN * IND;      // [8192][8192]

  float* ws = (float*)d_ws;
  size_t off = 0;
  auto alloc = [&](size_t nfloats) {
    float* p = ws + off;
    off += (nfloats + 255) & ~(size_t)255;
    return p;
  };
  float* Wh = alloc((size_t)NN * 128);
  float* z = alloc((size_t)NN * 128);
  float* valsum = alloc(NN);
  // contiguous zero region: cs(256) f1(8192) f2(8192) sumsA(512) sumsqA(512)
  //                         sumsB(1536) sumsqB(1536)
  const size_t ZTOT = 256 + 8192 + 8192 + 512 + 512 + 1536 + 1536;
  float* zbase = alloc(ZTOT);
  float* cs = zbase;
  float* f1 = zbase + 256;
  float* f2 = zbase + 256 + 8192;
  float* sumsA = zbase + 256 + 16384;
  float* sumsqA = sumsA + 512;
  float* sumsB = sumsqA + 512;
  float* sumsqB = sumsB + 1536;
  float* valA = alloc((size_t)NN * MAXNZ);
  int* idxA = (int*)alloc((size_t)NN * MAXNZ);
  int* nnzA = (int*)alloc(NN);
  __hip_bfloat16* tbuf = (__hip_bfloat16*)alloc((size_t)NN * 256);  // [8192][512] bf16
  __hip_bfloat16* gb = (__hip_bfloat16*)alloc((size_t)NN * 64);
  __hip_bfloat16* s1b = (__hip_bfloat16*)alloc((size_t)NN * 128);
  __hip_bfloat16* ghb = (__hip_bfloat16*)alloc((size_t)NN * 128);
  __hip_bfloat16* Wt = (__hip_bfloat16*)alloc((size_t)NPAD * 128);
  __hip_bfloat16* Wcatb = (__hip_bfloat16*)alloc(512 * 64);
  __hip_bfloat16* featb = (__hip_bfloat16*)alloc((size_t)NN * NPAD / 2);

  hipMemsetAsync(zbase, 0, ZTOT * sizeof(float), stream);

  // --- weights prep (independent) ---
  prep_k<<<NPAD, 256, 0, stream>>>(W_fd2, W_fd1, W_sd1, Wt, Wcatb);

  // --- GAT encoder ---
  gemm_att_k<<<dim3(NN / 64, 2), 256, 0, stream>>>(x, W_att, a_att, Wh, cs, f1, f2);
  extract_attn_k<<<NN / 4, 256, 0, stream>>>(adj, Wh, f1, f2, cs, nnzA, idxA, valA,
                                             valsum, z);
  gather_z_k<<<NN / 4, 256, 0, stream>>>(z, nnzA, idxA, valA, gb);

  // --- t = relu(g @ [W_fd1|W_sd1]) bf16 (MFMA, fused BN1/BN3 stats) ---
  mfma_bt_k<1><<<64 * 4, 256, 0, stream>>>((const short*)gb, (const short*)Wcatb,
                                           tbuf, 512, 4, sumsA, sumsqA);
  s1_gather_k<<<NN, 256, 0, stream>>>(tbuf, nnzA, idxA, valA, valsum, sumsA, sumsqA,
                                      bn1g, bn1b, bn3g, bn3b, s1b, ghb);

  // --- fused tail: feat GEMM (+BN2 stats) interleaved with struct sym ---
  tail_k<<<2848, 256, 0, stream>>>((const short*)ghb, (const short*)Wt, featb,
                                   sumsB, sumsqB, (const short*)s1b, struct_out);
  feat_apply_k<<<NN, 256, 0, stream>>>(featb, sumsB, sumsqB, bn2g, bn2b, feat_out);
}